// Round 1
// baseline (498.078 us; speedup 1.0000x reference)
//
#include <hip/hip_runtime.h>
#include <hip/hip_bf16.h>

// Problem constants (fixed by setup_inputs)
#define T_STEPS 512
#define BATCH   256
#define NN      128                 // n
#define NEMB    1024                // N
#define M_ROWS  (T_STEPS * BATCH)   // 131072
#define NOISE_K 0.13416407864998738f  // sqrt(2/alpha * sigma^2)

typedef short s16x8 __attribute__((ext_vector_type(8)));
typedef float f32x4 __attribute__((ext_vector_type(4)));

__device__ __forceinline__ unsigned short f2bf(float f) {
  union { float f; unsigned u; } v; v.f = f;
  unsigned r = v.u + 0x7fffu + ((v.u >> 16) & 1u);  // RNE
  return (unsigned short)(r >> 16);
}
__device__ __forceinline__ float bf2f(unsigned short s) {
  union { unsigned u; float f; } v; v.u = ((unsigned)s) << 16;
  return v.f;
}

// ---------------------------------------------------------------------------
// Kernel 1: leaky-RNN recurrence. One block per batch element b.
// threads: tid = i*2 + h ; thread sums W_rec[i, h*64 .. h*64+63] * x[k].
// x kept in LDS (+ a private register copy per (i,h) pair).
// states (bf16) written to ws in (T, B, n) layout; row m = t*B + b.
// ---------------------------------------------------------------------------
__global__ __launch_bounds__(256) void rnn_step_kernel(
    const float* __restrict__ u,          // (6, T, B)
    const float* __restrict__ rec_noise,  // (B, T, n)
    const float* __restrict__ inp_noise,  // (B, T, 6)
    const float* __restrict__ W_inp,      // (n, 6)
    const float* __restrict__ W_rec,      // (n, n)
    unsigned short* __restrict__ states)  // (T, B, n) bf16
{
  const int b   = blockIdx.x;
  const int tid = threadIdx.x;
  const int i   = tid >> 1;
  const int h   = tid & 1;

  __shared__ float x_lds[NN];
  __shared__ float u_s[8];

  // W_rec half-row into registers (64 fp32)
  float4 w[16];
  {
    const float4* wr = (const float4*)(W_rec + i * NN + h * 64);
    #pragma unroll
    for (int c = 0; c < 16; ++c) w[c] = wr[c];
  }
  float winp[6];
  #pragma unroll
  for (int j = 0; j < 6; ++j) winp[j] = W_inp[i * 6 + j];

  if (tid < NN) x_lds[tid] = 0.f;
  if (h == 0) states[(0 * BATCH + b) * NN + i] = 0;  // t=0 state is zero
  __syncthreads();

  // prefetch step-0 inputs
  float rn_cur = rec_noise[(b * T_STEPS + 0) * NN + i];
  float uu = 0.f, in_n = 0.f;
  if (tid < 6) {
    uu   = u[tid * (T_STEPS * BATCH) + 0 * BATCH + b];
    in_n = inp_noise[(b * T_STEPS + 0) * 6 + tid];
  }

  float xr = 0.f;  // private copy of x[i]
  for (int t = 0; t < T_STEPS - 1; ++t) {
    if (tid < 6) u_s[tid] = uu + NOISE_K * in_n;   // stage inputs for step t
    float rn = rn_cur;
    if (t < T_STEPS - 2) {                          // prefetch step t+1
      rn_cur = rec_noise[(b * T_STEPS + (t + 1)) * NN + i];
      if (tid < 6) {
        uu   = u[tid * (T_STEPS * BATCH) + (t + 1) * BATCH + b];
        in_n = inp_noise[(b * T_STEPS + (t + 1)) * 6 + tid];
      }
    }

    float acc = 0.f;
    #pragma unroll
    for (int c = 0; c < 16; ++c) {
      float4 xv = *(const float4*)&x_lds[h * 64 + c * 4];
      acc = fmaf(w[c].x, xv.x, acc);
      acc = fmaf(w[c].y, xv.y, acc);
      acc = fmaf(w[c].z, xv.z, acc);
      acc = fmaf(w[c].w, xv.w, acc);
    }
    acc += __shfl_xor(acc, 1);

    __syncthreads();  // all x_lds reads done; u_s visible

    float inp = 0.f;
    #pragma unroll
    for (int j = 0; j < 6; ++j) inp = fmaf(winp[j], u_s[j], inp);
    float pre = acc + inp;
    float r   = pre > 0.f ? pre : 0.f;
    float xn  = 0.9f * xr + 0.1f * (r + NOISE_K * rn);
    xr = xn;

    if (h == 0) {
      x_lds[i] = xn;
      states[((t + 1) * BATCH + b) * NN + i] = f2bf(xn);
    }
    __syncthreads();  // new x visible before next step
  }
}

// ---------------------------------------------------------------------------
// Kernel 2: states_embedded = states @ q, written transposed: out[j*M + m].
// Tile: 128 m x 64 j per block, 4 waves (each 32 m x 64 j), K = 128.
// q staged in LDS as bf16, XOR-swizzled on 16B units for conflict-free b128.
// A fragments loaded straight from global (L2-reused across the 16 j-tiles).
// ---------------------------------------------------------------------------
__global__ __launch_bounds__(256) void emb_kernel(
    const unsigned short* __restrict__ states,  // (M, n) bf16
    const float* __restrict__ q,                // (n, NEMB)
    float* __restrict__ out)                    // out[j*M + m]
{
  const int jt  = blockIdx.x;   // 0..15  (fast dim -> j-tiles of one m-panel co-resident)
  const int mt  = blockIdx.y;   // 0..1023
  const int tid = threadIdx.x;
  const int w   = tid >> 6;
  const int l   = tid & 63;
  const int lg  = l >> 4;       // 0..3
  const int lr  = l & 15;

  __shared__ unsigned short qt[64 * 128];  // [j][k], swizzled, 16 KB

  // stage q tile -> bf16 LDS (coalesced global reads)
  {
    const int j  = tid & 63;
    const int k0 = tid >> 6;
    #pragma unroll
    for (int kk = k0; kk < 128; kk += 4) {
      float v = q[kk * NEMB + jt * 64 + j];
      int k8 = kk >> 3, e = kk & 7;
      qt[j * 128 + ((k8 ^ (j & 7)) << 3) + e] = f2bf(v);
    }
  }

  // A fragments from global: row = l&15, k-chunk = (l>>4)*8 within each K=32
  s16x8 afrag[2][4];
  #pragma unroll
  for (int mf = 0; mf < 2; ++mf) {
    const int m = mt * 128 + w * 32 + mf * 16 + lr;
    const unsigned short* arow = states + m * NN;
    #pragma unroll
    for (int kc = 0; kc < 4; ++kc)
      afrag[mf][kc] = *(const s16x8*)(arow + kc * 32 + lg * 8);
  }
  __syncthreads();

  f32x4 acc[2][4] = {};
  #pragma unroll
  for (int kc = 0; kc < 4; ++kc) {
    s16x8 bfrag[4];
    #pragma unroll
    for (int jf = 0; jf < 4; ++jf) {
      const int jl = jf * 16 + lr;
      bfrag[jf] = *(const s16x8*)(qt + jl * 128 + ((((kc << 2) + lg) ^ (jl & 7)) << 3));
    }
    #pragma unroll
    for (int mf = 0; mf < 2; ++mf)
      #pragma unroll
      for (int jf = 0; jf < 4; ++jf)
        acc[mf][jf] = __builtin_amdgcn_mfma_f32_16x16x32_bf16(
            afrag[mf][kc], bfrag[jf], acc[mf][jf], 0, 0, 0);
  }

  // epilogue: per-lane float4 along m (D: col=lane&15 -> j, row=(lane>>4)*4+reg -> m)
  #pragma unroll
  for (int mf = 0; mf < 2; ++mf) {
    const int m = mt * 128 + w * 32 + mf * 16 + lg * 4;
    #pragma unroll
    for (int jf = 0; jf < 4; ++jf) {
      const long j = jt * 64 + jf * 16 + lr;
      *(f32x4*)&out[j * M_ROWS + m] = acc[mf][jf];
    }
  }
}

// ---------------------------------------------------------------------------
// Kernel 3: outputs = states @ W_out^T  ->  out[(1024+j)*M + m]
// ---------------------------------------------------------------------------
__global__ __launch_bounds__(256) void wout_kernel(
    const unsigned short* __restrict__ states,  // (M, n) bf16
    const float* __restrict__ W_out,            // (2, n)
    float* __restrict__ out)
{
  __shared__ float wo[2 * NN];
  const int tid = threadIdx.x;
  wo[tid] = W_out[tid];
  __syncthreads();

  const int m = blockIdx.x * 256 + tid;
  const unsigned short* row = states + (size_t)m * NN;
  float a0 = 0.f, a1 = 0.f;
  #pragma unroll
  for (int c = 0; c < 16; ++c) {
    s16x8 v = *(const s16x8*)(row + c * 8);
    #pragma unroll
    for (int e = 0; e < 8; ++e) {
      float x = bf2f((unsigned short)v[e]);
      a0 = fmaf(x, wo[c * 8 + e], a0);
      a1 = fmaf(x, wo[NN + c * 8 + e], a1);
    }
  }
  out[(long)1024 * M_ROWS + m] = a0;
  out[(long)1025 * M_ROWS + m] = a1;
}

extern "C" void kernel_launch(void* const* d_in, const int* in_sizes, int n_in,
                              void* d_out, int out_size, void* d_ws, size_t ws_size,
                              hipStream_t stream) {
  const float* u         = (const float*)d_in[0];
  const float* rec_noise = (const float*)d_in[1];
  const float* inp_noise = (const float*)d_in[2];
  const float* W_inp     = (const float*)d_in[3];
  const float* W_rec     = (const float*)d_in[4];
  const float* W_out     = (const float*)d_in[5];
  const float* q         = (const float*)d_in[6];
  float* out = (float*)d_out;
  unsigned short* states = (unsigned short*)d_ws;  // (T, B, n) bf16 = 33.6 MB

  rnn_step_kernel<<<dim3(BATCH), dim3(256), 0, stream>>>(
      u, rec_noise, inp_noise, W_inp, W_rec, states);

  dim3 g2(NEMB / 64, M_ROWS / 128);  // (16, 1024), jt fastest for A-panel L2 reuse
  emb_kernel<<<g2, dim3(256), 0, stream>>>(states, q, out);

  wout_kernel<<<dim3(M_ROWS / 256), dim3(256), 0, stream>>>(states, W_out, out);
}